// Round 1
// baseline (812.952 us; speedup 1.0000x reference)
//
#include <hip/hip_runtime.h>
#include <math.h>

#define NTH 256

// float4 index of S cell (row i, col-chunk m): rotate-by-chunk swizzle,
// makes GJ row reads / col reads / matvec reads all <=2-way bank conflicts.
__device__ __forceinline__ int SC4(int i, int m) { return m * 64 + ((i + m) & 63); }

// S[i][j] = sum_c A[i][c] * w[c] * A[j][c]   (full 64x64, 4x4 block per thread)
__device__ __forceinline__ void form_S(const float* __restrict__ As,
                                       const float* __restrict__ wv,
                                       float* __restrict__ Sb, int t)
{
  const int bi = t >> 4, bj = t & 15;
  float a00=0,a01=0,a02=0,a03=0, a10=0,a11=0,a12=0,a13=0;
  float a20=0,a21=0,a22=0,a23=0, a30=0,a31=0,a32=0,a33=0;
  const float4* As4 = (const float4*)As;
  for (int c = 0; c < 256; ++c) {
    float4 a4 = As4[c * 16 + bi];   // A[4bi..4bi+3][c]
    float4 b4 = As4[c * 16 + bj];   // A[4bj..4bj+3][c]
    float wc = wv[c];
    float bx = b4.x * wc, by = b4.y * wc, bz = b4.z * wc, bw = b4.w * wc;
    a00 += a4.x*bx; a01 += a4.x*by; a02 += a4.x*bz; a03 += a4.x*bw;
    a10 += a4.y*bx; a11 += a4.y*by; a12 += a4.y*bz; a13 += a4.y*bw;
    a20 += a4.z*bx; a21 += a4.z*by; a22 += a4.z*bz; a23 += a4.z*bw;
    a30 += a4.w*bx; a31 += a4.w*by; a32 += a4.w*bz; a33 += a4.w*bw;
  }
  float4* Sb4 = (float4*)Sb;
  Sb4[SC4(4*bi+0, bj)] = make_float4(a00,a01,a02,a03);
  Sb4[SC4(4*bi+1, bj)] = make_float4(a10,a11,a12,a13);
  Sb4[SC4(4*bi+2, bj)] = make_float4(a20,a21,a22,a23);
  Sb4[SC4(4*bi+3, bj)] = make_float4(a30,a31,a32,a33);
}

// In-place Gauss-Jordan inversion of SPD 64x64 (no pivoting), rank-1, 2 barriers/step.
__device__ __forceinline__ void gj_invert(float* __restrict__ Sb,
                                          float* __restrict__ tmp,
                                          float* __restrict__ colb, int t)
{
  float4* Sb4 = (float4*)Sb;
  float4* tmp4 = (float4*)tmp;
  const int i = t & 63, mb = t >> 6;
  for (int j = 0; j < 64; ++j) {
    const int mj = j >> 2, ej = j & 3;
    if (t < 16) {                    // stage scaled pivot row: tmp = S[j][:] / p, tmp[j]=1/p
      const int m = t;
      float pj = Sb[mj * 256 + 4 * ((j + mj) & 63) + ej];
      float invp = 1.0f / pj;
      float4 s4 = Sb4[SC4(j, m)];
      float4 v = make_float4(s4.x*invp, s4.y*invp, s4.z*invp, s4.w*invp);
      if (m == mj) {
        if (ej == 0) v.x = invp; else if (ej == 1) v.y = invp;
        else if (ej == 2) v.z = invp; else v.w = invp;
      }
      tmp4[m] = v;
    } else if (t >= 64 && t < 128) { // stage old column j
      const int ii = t - 64;
      colb[ii] = Sb[mj * 256 + 4 * ((ii + mj) & 63) + ej];
    }
    __syncthreads();
    const float ci = colb[i];
    #pragma unroll
    for (int q = 0; q < 4; ++q) {
      const int m = mb + 4 * q;
      float4 s4 = Sb4[SC4(i, m)];
      float4 t4 = tmp4[m];
      float4 r = make_float4(s4.x - ci*t4.x, s4.y - ci*t4.y,
                             s4.z - ci*t4.z, s4.w - ci*t4.w);
      if (m == mj) {
        float iv = (ej == 0) ? t4.x : (ej == 1) ? t4.y : (ej == 2) ? t4.z : t4.w;
        float nv = -ci * iv;
        if (ej == 0) r.x = nv; else if (ej == 1) r.y = nv;
        else if (ej == 2) r.z = nv; else r.w = nv;
      }
      if (i == j) r = t4;
      Sb4[SC4(i, m)] = r;
    }
    __syncthreads();
  }
}

// out[i] = sum_j Sinv[i][j] * r[j]   (threads 0..63)
__device__ __forceinline__ void matS(const float* __restrict__ Sb,
                                     const float* __restrict__ r,
                                     float* __restrict__ outv, int t)
{
  if (t < 64) {
    const float4* Sb4 = (const float4*)Sb;
    const float4* r4 = (const float4*)r;
    float acc = 0.f;
    #pragma unroll
    for (int m = 0; m < 16; ++m) {
      float4 s4 = Sb4[SC4(t, m)];
      float4 rr = r4[m];
      acc += s4.x*rr.x + s4.y*rr.y + s4.z*rr.z + s4.w*rr.w;
    }
    outv[t] = acc;
  }
}

__global__ __launch_bounds__(NTH)
void optnet_kernel(const float* __restrict__ x,  const float* __restrict__ W1,
                   const float* __restrict__ b1, const float* __restrict__ W2,
                   const float* __restrict__ b2, const float* __restrict__ A,
                   float* __restrict__ out)
{
  extern __shared__ float sm[];
  const int b = blockIdx.x;
  const int t = threadIdx.x;
  const int lane = t & 63;
  const int wav = t >> 6;

  float* As   = sm;              // 16384: A^T c-major, As[c*64+k] = A[k][c]
  float* Sb   = sm + 16384;      // 4096:  S / Sinv (swizzled chunk-major)
  float* xld  = Sb;              // alias (first 1024) during h-compute
  float* h    = sm + 20480;      // 256
  float* z    = h + 256;         // 256
  float* wHd  = z + 256;         // 256: 1/Hd
  float* wtp  = wHd + 256;       // 256: top/Hd (A@v operand)
  float* part = wtp + 256;       // 256: matvec partials
  float* nu   = part + 256;      // 64
  float* rev  = nu + 64;         // 64: re
  float* dnu  = rev + 64;        // 64
  float* rhs  = dnu + 64;        // 64
  float* tmp  = rhs + 64;        // 64: GJ pivot row
  float* colb = tmp + 64;        // 64: GJ pivot col
  float* red  = colb + 64;       // 16: reductions

  // ---- stage A^T (c-major) and x row ----
  for (int g = t; g < 64 * 256; g += NTH)
    As[(g & 255) * 64 + (g >> 8)] = A[g];          // A row-major (k,c)
  for (int g = t; g < 1024; g += NTH)
    xld[g] = x[b * 1024 + g];
  __syncthreads();

  // ---- h = relu(x @ W1^T + b1): wave-cooperative, coalesced W1 reads ----
  {
    const float4* xr = (const float4*)xld;
    for (int jj = 0; jj < 64; ++jj) {
      int j = (wav << 6) + jj;
      const float4* w1r = (const float4*)(W1 + (size_t)j * 1024);
      float acc = 0.f;
      #pragma unroll
      for (int mm = 0; mm < 4; ++mm) {
        float4 a = w1r[lane + (mm << 6)];
        float4 xv = xr[lane + (mm << 6)];
        acc += a.x*xv.x + a.y*xv.y + a.z*xv.z + a.w*xv.w;
      }
      #pragma unroll
      for (int off = 32; off > 0; off >>= 1) acc += __shfl_xor(acc, off, 64);
      if (lane == 0) {
        float v = acc + b1[j];
        h[j] = v > 0.f ? v : 0.f;
      }
    }
  }
  __syncthreads();                // h ready; xld (Sb alias) free from here

  const float hr = h[t];

  // ---- initial solve: K0 = [0.1*I, A^T; A, 0], rhs = [h; 1] ----
  wHd[t] = 10.0f;                 // 1/QPEN
  wtp[t] = hr * 10.0f;
  __syncthreads();
  form_S(As, wHd, Sb, t);
  __syncthreads();
  gj_invert(Sb, tmp, colb, t);
  {                               // rhs = A @ (h/QPEN) - 1
    float acc = 0.f;
    #pragma unroll 8
    for (int cc = 0; cc < 64; ++cc) {
      int c = (wav << 6) + cc;
      acc += wtp[c] * As[c * 64 + lane];
    }
    part[t] = acc;
  }
  __syncthreads();
  if (t < 64) rhs[t] = part[t] + part[64 + t] + part[128 + t] + part[192 + t] - 1.0f;
  __syncthreads();
  matS(Sb, rhs, nu, t);
  __syncthreads();

  float zt, st, lt;
  {                               // z0 = (h - A^T nu)/QPEN ; s0 = max(z0,1); lam0 = 1
    float atd = 0.f;
    #pragma unroll 8
    for (int ss = 0; ss < 64; ++ss) {
      int k = (lane + ss) & 63;   // skewed -> conflict-free column dot
      atd += As[t * 64 + k] * nu[k];
    }
    zt = (hr - atd) * 10.0f;
    z[t] = zt;
    st = fmaxf(zt, 1.0f);
    lt = 1.0f;
  }
  __syncthreads();

  // ---- 12 predictor-corrector IP iterations ----
  for (int it = 0; it < 12; ++it) {
    float nuA = 0.f;
    #pragma unroll 8
    for (int ss = 0; ss < 64; ++ss) {
      int k = (lane + ss) & 63;
      nuA += As[t * 64 + k] * nu[k];
    }
    const float rxt = 0.1f * zt - hr - lt + nuA;   // rx = QPEN*z + p - lam + nu@A, p=-h
    const float rit = st - zt;
    const float Dt  = lt / st;
    const float wt  = 1.0f / (0.1f + Dt);          // 1/Hd
    wHd[t] = wt;
    {                                              // re partials: z @ A^T - 1
      float acc = 0.f;
      #pragma unroll 8
      for (int cc = 0; cc < 64; ++cc) {
        int c = (wav << 6) + cc;
        acc += z[c] * As[c * 64 + lane];
      }
      part[t] = acc;
    }
    __syncthreads();
    if (t < 64) rev[t] = part[t] + part[64 + t] + part[128 + t] + part[192 + t] - 1.0f;
    form_S(As, wHd, Sb, t);
    __syncthreads();
    gj_invert(Sb, tmp, colb, t);

    // ---- solve 1 (affine): rs = lam*s ----
    const float rs1 = lt * st;
    const float g1  = (lt * rit - rs1) / st;
    const float top1 = -rxt + g1;
    wtp[t] = top1 * wt;
    __syncthreads();
    {
      float acc = 0.f;
      #pragma unroll 8
      for (int cc = 0; cc < 64; ++cc) {
        int c = (wav << 6) + cc;
        acc += wtp[c] * As[c * 64 + lane];
      }
      part[t] = acc;
    }
    __syncthreads();
    if (t < 64) rhs[t] = part[t] + part[64 + t] + part[128 + t] + part[192 + t] + rev[t];
    __syncthreads();
    matS(Sb, rhs, dnu, t);
    __syncthreads();
    float dsa, dla;
    {
      float atd = 0.f;
      #pragma unroll 8
      for (int ss = 0; ss < 64; ++ss) {
        int k = (lane + ss) & 63;
        atd += As[t * 64 + k] * dnu[k];
      }
      float dza = (top1 - atd) * wt;
      dsa = dza - rit;
      dla = g1 - Dt * dza;
    }
    {                                              // step_len affine
      float r1 = dsa < 0.f ? -st / dsa : 1e10f;
      float r2 = dla < 0.f ? -lt / dla : 1e10f;
      float mn = fminf(r1, r2);
      #pragma unroll
      for (int off = 32; off > 0; off >>= 1) mn = fminf(mn, __shfl_xor(mn, off, 64));
      if (lane == 0) red[wav] = mn;
    }
    __syncthreads();
    const float a_aff = fminf(1.0f, 0.999f * fminf(fminf(red[0], red[1]), fminf(red[2], red[3])));
    {                                              // mu, mu_aff sums
      float p1 = st * lt;
      float p2 = (st + a_aff * dsa) * (lt + a_aff * dla);
      #pragma unroll
      for (int off = 32; off > 0; off >>= 1) {
        p1 += __shfl_xor(p1, off, 64);
        p2 += __shfl_xor(p2, off, 64);
      }
      if (lane == 0) { red[4 + wav] = p1; red[8 + wav] = p2; }
    }
    __syncthreads();
    const float mu  = (red[4] + red[5] + red[6] + red[7])   * (1.0f / 256.0f);
    const float mua = (red[8] + red[9] + red[10] + red[11]) * (1.0f / 256.0f);
    float sig = mua / mu; sig = sig * sig * sig;
    const float smu = sig * mu;

    // ---- solve 2 (corrector): rs = lam*s + dsa*dla - sigma*mu ----
    const float rs2 = lt * st + dsa * dla - smu;
    const float g2  = (lt * rit - rs2) / st;
    const float top2 = -rxt + g2;
    wtp[t] = top2 * wt;
    __syncthreads();
    {
      float acc = 0.f;
      #pragma unroll 8
      for (int cc = 0; cc < 64; ++cc) {
        int c = (wav << 6) + cc;
        acc += wtp[c] * As[c * 64 + lane];
      }
      part[t] = acc;
    }
    __syncthreads();
    if (t < 64) rhs[t] = part[t] + part[64 + t] + part[128 + t] + part[192 + t] + rev[t];
    __syncthreads();
    matS(Sb, rhs, dnu, t);
    __syncthreads();
    float dz2, ds2, dl2;
    {
      float atd = 0.f;
      #pragma unroll 8
      for (int ss = 0; ss < 64; ++ss) {
        int k = (lane + ss) & 63;
        atd += As[t * 64 + k] * dnu[k];
      }
      dz2 = (top2 - atd) * wt;
      ds2 = dz2 - rit;
      dl2 = g2 - Dt * dz2;
    }
    {                                              // step_len final
      float r1 = ds2 < 0.f ? -st / ds2 : 1e10f;
      float r2 = dl2 < 0.f ? -lt / dl2 : 1e10f;
      float mn = fminf(r1, r2);
      #pragma unroll
      for (int off = 32; off > 0; off >>= 1) mn = fminf(mn, __shfl_xor(mn, off, 64));
      if (lane == 0) red[wav] = mn;
    }
    __syncthreads();
    const float a = fminf(1.0f, 0.999f * fminf(fminf(red[0], red[1]), fminf(red[2], red[3])));

    zt = zt + a * dz2;
    st = fmaxf(st + a * ds2, 1e-8f);
    lt = fmaxf(lt + a * dl2, 1e-8f);
    z[t] = zt;
    if (t < 64) nu[t] += a * dnu[t];
    __syncthreads();
  }

  // ---- logits = z @ W2^T + b2 ; log_softmax ----
  if (t < 160) {
    int cls = t >> 4, pp = t & 15;
    float acc = 0.f;
    #pragma unroll
    for (int e = 0; e < 16; ++e) {
      int c = (pp << 4) + e;
      acc += z[c] * W2[cls * 256 + c];
    }
    part[t] = acc;
  }
  __syncthreads();
  if (t < 10) {
    float s = b2[t];
    #pragma unroll
    for (int pp = 0; pp < 16; ++pp) s += part[(t << 4) + pp];
    red[t] = s;
  }
  __syncthreads();
  if (t == 0) {
    float mx = red[0];
    #pragma unroll
    for (int c = 1; c < 10; ++c) mx = fmaxf(mx, red[c]);
    float se = 0.f;
    #pragma unroll
    for (int c = 0; c < 10; ++c) se += expf(red[c] - mx);
    float lse = mx + logf(se);
    for (int c = 0; c < 10; ++c) out[b * 10 + c] = red[c] - lse;
  }
}

extern "C" void kernel_launch(void* const* d_in, const int* in_sizes, int n_in,
                              void* d_out, int out_size, void* d_ws, size_t ws_size,
                              hipStream_t stream) {
  (void)in_sizes; (void)n_in; (void)out_size; (void)d_ws; (void)ws_size;
  const float* x  = (const float*)d_in[0];
  const float* W1 = (const float*)d_in[1];
  const float* b1 = (const float*)d_in[2];
  const float* W2 = (const float*)d_in[3];
  const float* b2 = (const float*)d_in[4];
  const float* A  = (const float*)d_in[5];
  float* out = (float*)d_out;

  const size_t shmem = (16384 + 4096 + 5 * 256 + 6 * 64 + 16) * sizeof(float); // 88640 B
  // >64KB dynamic LDS: set opt-in attribute (host-side config, capture-safe; idempotent)
  (void)hipFuncSetAttribute((const void*)optnet_kernel,
                            hipFuncAttributeMaxDynamicSharedMemorySize, (int)shmem);
  optnet_kernel<<<128, NTH, shmem, stream>>>(x, W1, b1, W2, b2, A, out);
}